// Round 4
// baseline (1124.941 us; speedup 1.0000x reference)
//
#include <hip/hip_runtime.h>
#include <math.h>

#define V_N 100000
#define D_N 300
#define K_N 200
#define B_N 256

#define SC 128.0f
#define SC_INV 0.0078125f

typedef _Float16 h4 __attribute__((ext_vector_type(4)));
typedef _Float16 h8 __attribute__((ext_vector_type(8)));
typedef float f4v __attribute__((ext_vector_type(4)));

typedef __attribute__((address_space(1))) const void gvoid;
typedef __attribute__((address_space(3))) void lvoid;

// ---------------- workspace layout (floats) ----------------
// P  : 20,000,000 (logp, K x V fp32)
// CB : 225,280 floats = 450,560 halves  (LDS image: [kb2][c10]{6 arrays [n112][32] swizzled + pad to 22528 halves})
// scalars: alpha,s,hic (256 each)
// pm/ps: 800 each (partial softmax stats)
// yF : reuses CB region (halves) after logp is done
static constexpr size_t P_OFF     = 0;
static constexpr size_t CB_OFF    = (size_t)K_N * V_N;            // 20,000,000
static constexpr size_t ALPHA_OFF = CB_OFF + 225280;
static constexpr size_t S_OFF     = ALPHA_OFF + 256;
static constexpr size_t HIC_OFF   = S_OFF + 256;
static constexpr size_t PM_OFF    = HIC_OFF + 256;
static constexpr size_t PS_OFF    = PM_OFF + 800;
static constexpr size_t YF_OFF    = CB_OFF;   // overlap (halves)

// ---------------- kernel A (fused): per-topic scalars + B LDS image --------
// blocks 0..1759: coef_prep path; blocks 1760..2015: topic_prep path (k = b-1760)
__global__ __launch_bounds__(256) void fused_prep(
    const float* __restrict__ mu, const float* __restrict__ w,
    const float* __restrict__ cd,
    float* __restrict__ alpha, float* __restrict__ sArr,
    float* __restrict__ hic, _Float16* __restrict__ cB)
{
    __shared__ float4 red[256];
    int tid = threadIdx.x;
    if (blockIdx.x < 1760) {
        // ---- coef image: chunk slab (kb,c) = 22528 halves; 6 arrays x [n112][32]
        // swizzled: pos p holds source quad q = (p - (n>>1)) & 3; tail 1024 zero pad.
        // arr: 0/1 = hi/lo(-0.5*Dinv*SC_INV), 2/3 = hi/lo(mu*Dinv*SC_INV), 4/5 = hi/lo(u*SC_INV)
        int id = blockIdx.x * 256 + tid;
        int chunk = id / 22528;
        int rem   = id % 22528;
        int kb = chunk / 10, c = chunk % 10;
        _Float16 outv = (_Float16)0.f;
        if (rem < 21504) {
            int arr = rem / 3584;
            int r2  = rem % 3584;
            int n = r2 >> 5;
            int h = r2 & 31;
            int p = h >> 3, r = h & 7;
            int q = (p - (n >> 1)) & 3;
            int d = c * 32 + q * 8 + r;
            int topic = kb * 112 + n;
            if (topic < K_N && d < D_N) {
                float Di = 1.0f / cd[topic * D_N + d];
                float val;
                if (arr < 2)      val = -0.5f * Di * SC_INV;
                else if (arr < 4) val = mu[topic * D_N + d] * Di * SC_INV;
                else              val = w[topic * D_N + d] * Di * SC_INV;
                _Float16 hi = (_Float16)val;
                outv = (arr & 1) ? (_Float16)(val - (float)hi) : hi;
            }
        }
        cB[id] = outv;
        return;
    }
    // ---- topic scalars ----
    int k = blockIdx.x - 1760;
    if (k >= K_N) {
        if (tid == 0) { alpha[k] = 0.f; sArr[k] = 0.f; hic[k] = 0.f; }
        return;
    }
    float capp = 0.f, logd = 0.f, cpart = 0.f, spart = 0.f;
    for (int d = tid; d < D_N; d += 256) {
        float Dg = cd[k * D_N + d];
        float Di = 1.0f / Dg;
        float wvv = w[k * D_N + d];
        float m  = mu[k * D_N + d];
        float u  = wvv * Di;
        capp  += wvv * u;
        logd  += logf(Dg);
        cpart += m * m * Di;
        spart += m * u;
    }
    red[tid] = make_float4(capp, logd, cpart, spart);
    __syncthreads();
    for (int s = 128; s > 0; s >>= 1) {
        if (tid < s) {
            float4 a = red[tid], b = red[tid + s];
            red[tid] = make_float4(a.x + b.x, a.y + b.y, a.z + b.z, a.w + b.w);
        }
        __syncthreads();
    }
    if (tid == 0) {
        float4 r = red[0];
        float cap = 1.0f + r.x;
        float logdet = r.y + logf(cap);
        const float LOG2PI = 1.8378770664093453f;
        alpha[k] = -0.5f * ((float)D_N * LOG2PI + logdet + r.z);
        sArr[k]  = r.w;
        hic[k]   = 0.5f / cap;
    }
}

// ---------------- kernel B: logp via split-fp16 MFMA (v4) ----------------
// Block tile M=256 (V) x N=112 (topics), 8 waves stacked in M (wave 32x112).
// grid (2 kb, 391 vblk), 512 threads.
// A path: per-lane direct global loads -> in-register split-fp16 (no LDS).
// B path: SINGLE-buffered LDS slab (22528 halves = 45056 B) via global_load_lds,
// 2 barriers per chunk. LDS/block = 59136 B (epilogue Ct) -> 2 blocks/CU =
// 16 waves/CU = 4 waves/SIMD; the co-resident block covers the DMA drain.
__global__ __launch_bounds__(512, 4) void logp_mfma(
    const float* __restrict__ wv, const _Float16* __restrict__ cB,
    const float* __restrict__ alphaA, const float* __restrict__ sA,
    const float* __restrict__ hA, float* __restrict__ P)
{
    __shared__ _Float16 smem[29568];   // 59136 B: B slab (45056) / epilogue Ct

    const int tid = threadIdx.x;
    const int kb = blockIdx.x;
    const int v0 = blockIdx.y * 256;
    const int lane = tid & 63;
    const int quad = lane >> 4, lr = lane & 15;
    const int w = tid >> 6;            // wave 0..7
    const int wm = w * 32;

    const int gv0 = min(v0 + wm + lr,      V_N - 1);
    const int gv1 = min(v0 + wm + 16 + lr, V_N - 1);

    f4v C1[2][7], C2[2][7];
    #pragma unroll
    for (int i = 0; i < 2; ++i)
        #pragma unroll
        for (int j = 0; j < 7; ++j) {
            C1[i][j] = (f4v){0.f, 0.f, 0.f, 0.f};
            C2[i][j] = (f4v){0.f, 0.f, 0.f, 0.f};
        }

    float4 La0, Lb0, La1, Lb1;                 // A prefetch regs (rows row0,row1)
    h8 qh0, ql0, ah0, al0, qh1, ql1, ah1, al1; // A fragments

    auto ISSUE_A = [&](int cn) {
        int db = cn * 32 + (quad << 3);
        int dc = db > 292 ? 292 : db;          // clamp keeps loads in-bounds
        const float* p0 = wv + (size_t)gv0 * D_N + dc;
        const float* p1 = wv + (size_t)gv1 * D_N + dc;
        La0 = *(const float4*)(p0);
        Lb0 = *(const float4*)(p0 + 4);
        La1 = *(const float4*)(p1);
        Lb1 = *(const float4*)(p1 + 4);
    };

    auto ISSUE_B = [&](int cn) {
        const _Float16* slab = cB + (size_t)(kb * 10 + cn) * 22528 + tid * 8;
        _Float16* dst = smem + tid * 8;
        #pragma unroll
        for (int it = 0; it < 5; ++it)
            __builtin_amdgcn_global_load_lds(
                (gvoid*)(slab + it * 4096), (lvoid*)(dst + it * 4096), 16, 0, 0);
        if (tid < 256)   // wave-uniform tail (waves 0-3)
            __builtin_amdgcn_global_load_lds(
                (gvoid*)(slab + 5 * 4096), (lvoid*)(dst + 5 * 4096), 16, 0, 0);
    };

    auto CVT = [&](int c, const float4& La, const float4& Lb,
                   h8& qh, h8& ql, h8& ah, h8& al) {
        float xr[8];
        xr[0] = La.x; xr[1] = La.y; xr[2] = La.z; xr[3] = La.w;
        xr[4] = Lb.x; xr[5] = Lb.y; xr[6] = Lb.z; xr[7] = Lb.w;
        if (c == 9) {                          // d tail: chunk 9 covers d 288..319
            if (quad == 1) {                   // need 296..299, zero 300..303
                xr[0] = Lb.x; xr[1] = Lb.y; xr[2] = Lb.z; xr[3] = Lb.w;
                xr[4] = 0.f;  xr[5] = 0.f;  xr[6] = 0.f;  xr[7] = 0.f;
            } else if (quad > 1) {             // d >= 304: all zero
                #pragma unroll
                for (int j = 0; j < 8; ++j) xr[j] = 0.f;
            }
        }
        #pragma unroll
        for (int j = 0; j < 8; ++j) {
            float x = xr[j];
            _Float16 xh = (_Float16)x;
            ah[j] = xh;
            al[j] = (_Float16)(x - (float)xh);
            float xs = x * x;
            _Float16 sh = (_Float16)xs;
            qh[j] = sh;
            ql[j] = (_Float16)(xs - (float)sh);
        }
    };

    // prologue: A(0) in flight
    ISSUE_A(0);

    for (int c = 0; c < 10; ++c) {
        __syncthreads();   // all waves done reading the slab (prev chunk)
        ISSUE_B(c);
        __syncthreads();   // vmcnt(0) drain: slab(c) ready (A regs too)

        // convert current A regs -> fragments (frees the prefetch regs)
        CVT(c, La0, Lb0, qh0, ql0, ah0, al0);
        CVT(c, La1, Lb1, qh1, ql1, ah1, al1);
        // prefetch next chunk's A (hidden under this chunk's compute)
        if (c < 9) ISSUE_A(c + 1);

        const _Float16* Bsp = smem;
        h8 bf[7];
        #define LDB(arr)                                                       \
            _Pragma("unroll")                                                  \
            for (int nt = 0; nt < 7; ++nt) {                                   \
                int n = nt * 16 + lr;                                          \
                bf[nt] = *(const h8*)(Bsp + (arr) * 3584 + n * 32              \
                                      + (((quad + (n >> 1)) & 3) << 3));       \
            }
        #define MF(ACC, MT, FR)                                                \
            _Pragma("unroll")                                                  \
            for (int nt = 0; nt < 7; ++nt)                                     \
                ACC[MT][nt] = __builtin_amdgcn_mfma_f32_16x16x32_f16(          \
                    FR, bf[nt], ACC[MT][nt], 0, 0, 0);

        LDB(0)                    // hi(-0.5 Dinv)
        MF(C1, 0, qh0) MF(C1, 1, qh1) MF(C1, 0, ql0) MF(C1, 1, ql1)
        LDB(1)                    // lo(-0.5 Dinv)
        MF(C1, 0, qh0) MF(C1, 1, qh1)
        LDB(2)                    // hi(mu Dinv)
        MF(C1, 0, ah0) MF(C1, 1, ah1) MF(C1, 0, al0) MF(C1, 1, al1)
        LDB(3)                    // lo(mu Dinv)
        MF(C1, 0, ah0) MF(C1, 1, ah1)
        LDB(4)                    // hi(u)
        MF(C2, 0, ah0) MF(C2, 1, ah1) MF(C2, 0, al0) MF(C2, 1, al1)
        LDB(5)                    // lo(u)
        MF(C2, 0, ah0) MF(C2, 1, ah1)
        #undef LDB
        #undef MF
    }

    // ---- epilogue: combine, transpose via LDS (2 passes of 128 rows) ----
    __syncthreads();   // last chunk's slab reads done before Ct overwrites
    float* Ct = (float*)smem;  // [112][132] fp32 = 59136 B
    const int whalf = w >> 2;
    const int wmL = (w & 3) * 32;
    #pragma unroll
    for (int half = 0; half < 2; ++half) {
        if (whalf == half) {
            #pragma unroll
            for (int nt = 0; nt < 7; ++nt) {
                int nl = nt * 16 + lr;
                int ng = kb * 112 + nl;
                float alv = alphaA[ng], sk = sA[ng], hk = hA[ng];
                #pragma unroll
                for (int mt = 0; mt < 2; ++mt) {
                    f4v c1 = C1[mt][nt], c2 = C2[mt][nt];
                    f4v res;
                    #pragma unroll
                    for (int r = 0; r < 4; ++r) {
                        float t = SC * c2[r] - sk;
                        res[r] = alv + SC * c1[r] + hk * t * t;
                    }
                    *(f4v*)(Ct + nl * 132 + wmL + mt * 16 + quad * 4) = res;
                }
            }
        }
        __syncthreads();
        #pragma unroll
        for (int i = 0; i < 7; ++i) {
            int id = tid + i * 512;        // 0..3583
            int m4 = (id & 31) * 4;
            int nl = id >> 5;              // 0..111
            int kg = kb * 112 + nl;
            if (kg < K_N) {
                f4v val = *(const f4v*)(Ct + nl * 132 + m4);
                int v = v0 + half * 128 + m4;
                if (v + 3 < V_N) {
                    *(float4*)(P + (size_t)kg * V_N + v) =
                        make_float4(val[0], val[1], val[2], val[3]);
                } else {
                    for (int j = 0; j < 4; ++j)
                        if (v + j < V_N) P[(size_t)kg * V_N + v + j] = val[j];
                }
            }
        }
        __syncthreads();
    }
}

// ---------------- kernel C: partial softmax stats (4 parts per topic) ------
__global__ __launch_bounds__(256) void softmax_stats(
    const float* __restrict__ P, float* __restrict__ pm,
    float* __restrict__ ps)
{
    int k = blockIdx.x >> 2, part = blockIdx.x & 3;
    int tid = threadIdx.x;
    const float4* row = (const float4*)(P + (size_t)k * V_N) + part * 6250;
    float m = -INFINITY, s = 0.f;
    for (int i = tid; i < 6250; i += 256) {
        float4 x = row[i];
        float mx = fmaxf(fmaxf(x.x, x.y), fmaxf(x.z, x.w));
        if (mx > m) { s *= __expf(m - mx); m = mx; }
        s += __expf(x.x - m) + __expf(x.y - m)
           + __expf(x.z - m) + __expf(x.w - m);
    }
    __shared__ float ms[256], ss[256];
    ms[tid] = m; ss[tid] = s;
    __syncthreads();
    for (int off = 128; off > 0; off >>= 1) {
        if (tid < off) {
            float mo = ms[tid], so = ss[tid];
            float m2 = ms[tid + off], s2 = ss[tid + off];
            float mn = fmaxf(mo, m2);
            ms[tid] = mn;
            ss[tid] = so * __expf(mo - mn) + s2 * __expf(m2 - mn);
        }
        __syncthreads();
    }
    if (tid == 0) { pm[blockIdx.x] = ms[0]; ps[blockIdx.x] = ss[0]; }
}

// ---------------- kernel C2: yF (MFMA B-layout fp16) + x copy --------------
// yF[kc7][quad4][b256][j8] = x[b][kc*32+quad*8+j] / Z[k]  (0 for k>=200)
// Z merged inline from pm/ps (exact same sequential order as old stats_merge).
__global__ __launch_bounds__(256) void prep_y(
    const float* __restrict__ x,
    const float* __restrict__ pm, const float* __restrict__ ps,
    _Float16* __restrict__ yF, float* __restrict__ out)
{
    int id = blockIdx.x * 256 + threadIdx.x;
    if (id < 57344) {
        int j = id & 7;
        int b = (id >> 3) & 255;
        int q = (id >> 11) & 3;
        int kc = id >> 13;
        int k = kc * 32 + q * 8 + j;
        float v = 0.f;
        if (k < K_N) {
            float m = -INFINITY, s = 0.f;
            #pragma unroll
            for (int p = 0; p < 4; ++p) {
                float m2 = pm[k * 4 + p], s2 = ps[k * 4 + p];
                float mn = fmaxf(m, m2);
                s = s * __expf(m - mn) + s2 * __expf(m2 - mn);
                m = mn;
            }
            v = x[b * K_N + k] / s;
        }
        yF[id] = (_Float16)v;
    } else {
        int id2 = id - 57344;
        if (id2 < B_N * K_N) {
            int b = id2 / K_N, k = id2 % K_N;
            out[(size_t)b * (K_N + V_N) + k] = x[id2];
        }
    }
}

// ---------------- kernel D: out = y @ softmax-weights via fp16 MFMA --------
// b-tile = 256 (full B) -> P read from HBM exactly once; exp once per elem.
// Block: v-tile 64 (M, 4 waves x 1 mt), b-tile 256 (N, 16 nt). grid (1563).
// m_k merged inline from pm (max of 4 parts == old sequential merge).
__global__ __launch_bounds__(256) void out_gemm(
    const float* __restrict__ P, const _Float16* __restrict__ yF,
    const float* __restrict__ pm, float* __restrict__ out)
{
    __shared__ float Es[32][66];        // P chunk minus m_k; stride 66 (2-way reads)
    __shared__ _Float16 Ys[8192];       // y slab for current kc (16 KB)

    const int tid = threadIdx.x;
    const int v0 = blockIdx.x * 64;
    const int lane = tid & 63;
    const int quad = lane >> 4, lr = lane & 15;
    const int w = tid >> 6;
    const int row = w * 16 + lr;        // this wave's v-row within the tile

    f4v acc[16];
    #pragma unroll
    for (int i = 0; i < 16; ++i) acc[i] = (f4v){0.f, 0.f, 0.f, 0.f};

    const int kr = tid >> 3;       // 0..31 (staging row)
    const int vq = tid & 7;

    for (int kc = 0; kc < 7; ++kc) {
        __syncthreads();           // prior compute's LDS reads drained
        // ---- y slab DMA: 8192 halves, linear (layout already MFMA-B) ----
        {
            const _Float16* src = yF + (size_t)kc * 8192 + tid * 8;
            _Float16* dst = Ys + tid * 8;
            #pragma unroll
            for (int it = 0; it < 4; ++it)
                __builtin_amdgcn_global_load_lds(
                    (gvoid*)(src + it * 2048), (lvoid*)(dst + it * 2048),
                    16, 0, 0);
        }
        // ---- stage P chunk (32 k x 64 v), minus m_k ----
        int k = kc * 32 + kr;
        bool kok = k < K_N;
        float mk = 0.f;
        if (kok)
            mk = fmaxf(fmaxf(pm[k * 4], pm[k * 4 + 1]),
                       fmaxf(pm[k * 4 + 2], pm[k * 4 + 3]));
        #pragma unroll
        for (int i = 0; i < 2; ++i) {
            int vv = (vq + i * 8) * 4;
            float4 pv;
            if (kok && v0 + vv + 3 < V_N) {
                pv = *(const float4*)(P + (size_t)k * V_N + v0 + vv);
                pv = make_float4(pv.x - mk, pv.y - mk, pv.z - mk, pv.w - mk);
            } else {
                pv = make_float4(-1e30f, -1e30f, -1e30f, -1e30f);
            }
            *(float2*)&Es[kr][vv]     = make_float2(pv.x, pv.y);
            *(float2*)&Es[kr][vv + 2] = make_float2(pv.z, pv.w);
        }
        __syncthreads();           // drains DMA (vmcnt) + Es writes

        // ---- B fragments from LDS slab: col b = nt*16+lr, k = quad*8+j ----
        h8 yf[16];
        #pragma unroll
        for (int nt = 0; nt < 16; ++nt)
            yf[nt] = *(const h8*)(Ys + ((size_t)(quad * 256) + nt * 16 + lr) * 8);

        // ---- A fragment: row v = row, k = quad*8+j -> exp + cvt ----
        h8 af;
        #pragma unroll
        for (int j = 0; j < 8; ++j)
            af[j] = (_Float16)__expf(Es[quad * 8 + j][row]);

        #pragma unroll
        for (int nt = 0; nt < 16; ++nt)
            acc[nt] = __builtin_amdgcn_mfma_f32_16x16x32_f16(
                af, yf[nt], acc[nt], 0, 0, 0);
    }

    // store: C row = v (quad*4+reg), col = b (lr)
    int v = v0 + w * 16 + quad * 4;
    #pragma unroll
    for (int nt = 0; nt < 16; ++nt) {
        int b = nt * 16 + lr;
        float* dst = out + (size_t)b * (K_N + V_N) + K_N + v;
        f4v a = acc[nt];
        if (v + 3 < V_N) {
            *(float4*)dst = make_float4(a[0], a[1], a[2], a[3]);
        } else {
            for (int j = 0; j < 4; ++j)
                if (v + j < V_N) dst[j] = a[j];
        }
    }
}

// ---------------- launch ----------------
extern "C" void kernel_launch(void* const* d_in, const int* in_sizes, int n_in,
                              void* d_out, int out_size, void* d_ws, size_t ws_size,
                              hipStream_t stream) {
    const float* x    = (const float*)d_in[0];  // (B, K)
    const float* wv   = (const float*)d_in[1];  // (V, D)
    const float* mu   = (const float*)d_in[2];  // (K, D)
    const float* cw   = (const float*)d_in[3];  // (K, D)
    const float* cd   = (const float*)d_in[4];  // (K, D)
    float* out = (float*)d_out;
    float* ws  = (float*)d_ws;

    float* P      = ws + P_OFF;
    _Float16* cB  = (_Float16*)(ws + CB_OFF);
    float* alpha  = ws + ALPHA_OFF;
    float* sArr   = ws + S_OFF;
    float* hic    = ws + HIC_OFF;
    float* pm     = ws + PM_OFF;
    float* ps     = ws + PS_OFF;
    _Float16* yF  = (_Float16*)(ws + YF_OFF);   // overlaps cB (post-logp)

    fused_prep<<<2016, 256, 0, stream>>>(mu, cw, cd, alpha, sArr, hic, cB);

    dim3 gB(2, (V_N + 255) / 256);  // (2, 391)
    logp_mfma<<<gB, 512, 0, stream>>>(wv, cB, alpha, sArr, hic, P);

    softmax_stats<<<K_N * 4, 256, 0, stream>>>(P, pm, ps);
    prep_y<<<(57344 + B_N * K_N + 255) / 256, 256, 0, stream>>>(x, pm, ps, yF, out);

    out_gemm<<<(V_N + 63) / 64, 256, 0, stream>>>(P, yF, pm, out);
}

// Round 5
// 388.320 us; speedup vs baseline: 2.8969x; 2.8969x over previous
//
#include <hip/hip_runtime.h>
#include <math.h>

#define V_N 100000
#define D_N 300
#define K_N 200
#define B_N 256

#define SC 128.0f
#define SC_INV 0.0078125f

typedef _Float16 h4 __attribute__((ext_vector_type(4)));
typedef _Float16 h8 __attribute__((ext_vector_type(8)));
typedef float f4v __attribute__((ext_vector_type(4)));

typedef __attribute__((address_space(1))) const void gvoid;
typedef __attribute__((address_space(3))) void lvoid;

// ---------------- workspace layout (floats) ----------------
// P  : 20,000,000 (logp, K x V fp32)
// CB : 225,280 floats = 450,560 halves  (LDS image: [kb2][c10]{6 arrays [n112][32] swizzled + pad to 22528 halves})
// scalars: alpha,s,hic (256 each)
// pm/ps: 800 each (partial softmax stats)
// yF : reuses CB region (halves) after logp is done
static constexpr size_t P_OFF     = 0;
static constexpr size_t CB_OFF    = (size_t)K_N * V_N;            // 20,000,000
static constexpr size_t ALPHA_OFF = CB_OFF + 225280;
static constexpr size_t S_OFF     = ALPHA_OFF + 256;
static constexpr size_t HIC_OFF   = S_OFF + 256;
static constexpr size_t PM_OFF    = HIC_OFF + 256;
static constexpr size_t PS_OFF    = PM_OFF + 800;
static constexpr size_t YF_OFF    = CB_OFF;   // overlap (halves)

// ---------------- kernel A (fused): per-topic scalars + B LDS image --------
// blocks 0..1759: coef_prep path; blocks 1760..2015: topic_prep path (k = b-1760)
__global__ __launch_bounds__(256) void fused_prep(
    const float* __restrict__ mu, const float* __restrict__ w,
    const float* __restrict__ cd,
    float* __restrict__ alpha, float* __restrict__ sArr,
    float* __restrict__ hic, _Float16* __restrict__ cB)
{
    __shared__ float4 red[256];
    int tid = threadIdx.x;
    if (blockIdx.x < 1760) {
        // ---- coef image: chunk slab (kb,c) = 22528 halves; 6 arrays x [n112][32]
        // swizzled: pos p holds source quad q = (p - (n>>1)) & 3; tail 1024 zero pad.
        // arr: 0/1 = hi/lo(-0.5*Dinv*SC_INV), 2/3 = hi/lo(mu*Dinv*SC_INV), 4/5 = hi/lo(u*SC_INV)
        int id = blockIdx.x * 256 + tid;
        int chunk = id / 22528;
        int rem   = id % 22528;
        int kb = chunk / 10, c = chunk % 10;
        _Float16 outv = (_Float16)0.f;
        if (rem < 21504) {
            int arr = rem / 3584;
            int r2  = rem % 3584;
            int n = r2 >> 5;
            int h = r2 & 31;
            int p = h >> 3, r = h & 7;
            int q = (p - (n >> 1)) & 3;
            int d = c * 32 + q * 8 + r;
            int topic = kb * 112 + n;
            if (topic < K_N && d < D_N) {
                float Di = 1.0f / cd[topic * D_N + d];
                float val;
                if (arr < 2)      val = -0.5f * Di * SC_INV;
                else if (arr < 4) val = mu[topic * D_N + d] * Di * SC_INV;
                else              val = w[topic * D_N + d] * Di * SC_INV;
                _Float16 hi = (_Float16)val;
                outv = (arr & 1) ? (_Float16)(val - (float)hi) : hi;
            }
        }
        cB[id] = outv;
        return;
    }
    // ---- topic scalars ----
    int k = blockIdx.x - 1760;
    if (k >= K_N) {
        if (tid == 0) { alpha[k] = 0.f; sArr[k] = 0.f; hic[k] = 0.f; }
        return;
    }
    float capp = 0.f, logd = 0.f, cpart = 0.f, spart = 0.f;
    for (int d = tid; d < D_N; d += 256) {
        float Dg = cd[k * D_N + d];
        float Di = 1.0f / Dg;
        float wvv = w[k * D_N + d];
        float m  = mu[k * D_N + d];
        float u  = wvv * Di;
        capp  += wvv * u;
        logd  += logf(Dg);
        cpart += m * m * Di;
        spart += m * u;
    }
    red[tid] = make_float4(capp, logd, cpart, spart);
    __syncthreads();
    for (int s = 128; s > 0; s >>= 1) {
        if (tid < s) {
            float4 a = red[tid], b = red[tid + s];
            red[tid] = make_float4(a.x + b.x, a.y + b.y, a.z + b.z, a.w + b.w);
        }
        __syncthreads();
    }
    if (tid == 0) {
        float4 r = red[0];
        float cap = 1.0f + r.x;
        float logdet = r.y + logf(cap);
        const float LOG2PI = 1.8378770664093453f;
        alpha[k] = -0.5f * ((float)D_N * LOG2PI + logdet + r.z);
        sArr[k]  = r.w;
        hic[k]   = 0.5f / cap;
    }
}

// ---------------- kernel B: logp via split-fp16 MFMA (v5) ----------------
// Block tile M=256 (V) x N=112 (topics), 8 waves stacked in M (wave 32x112).
// grid (2 kb, 391 vblk), 512 threads.
// A path: per-lane direct global loads -> in-register split-fp16 (no LDS).
// B path: SINGLE-buffered LDS slab (22528 halves = 45056 B) via global_load_lds,
// 2 barriers per chunk. LDS/block = 59136 B (epilogue Ct) -> 2 blocks/CU by
// RESOURCES (108 VGPR <= 128, 2x59.4KB <= 160KB). launch_bounds kept at
// (512,2): the (512,4) bound forced a 128-VGPR budget and spilled (R4:
// WRITE_SIZE 2 GB, 918 us). Occupancy comes from resources, not the bound.
__global__ __launch_bounds__(512, 2) void logp_mfma(
    const float* __restrict__ wv, const _Float16* __restrict__ cB,
    const float* __restrict__ alphaA, const float* __restrict__ sA,
    const float* __restrict__ hA, float* __restrict__ P)
{
    __shared__ _Float16 smem[29568];   // 59136 B: B slab (45056) / epilogue Ct

    const int tid = threadIdx.x;
    const int kb = blockIdx.x;
    const int v0 = blockIdx.y * 256;
    const int lane = tid & 63;
    const int quad = lane >> 4, lr = lane & 15;
    const int w = tid >> 6;            // wave 0..7
    const int wm = w * 32;

    const int gv0 = min(v0 + wm + lr,      V_N - 1);
    const int gv1 = min(v0 + wm + 16 + lr, V_N - 1);

    f4v C1[2][7], C2[2][7];
    #pragma unroll
    for (int i = 0; i < 2; ++i)
        #pragma unroll
        for (int j = 0; j < 7; ++j) {
            C1[i][j] = (f4v){0.f, 0.f, 0.f, 0.f};
            C2[i][j] = (f4v){0.f, 0.f, 0.f, 0.f};
        }

    float4 La0, Lb0, La1, Lb1;                 // A prefetch regs (rows row0,row1)
    h8 qh0, ql0, ah0, al0, qh1, ql1, ah1, al1; // A fragments

    auto ISSUE_A = [&](int cn) {
        int db = cn * 32 + (quad << 3);
        int dc = db > 292 ? 292 : db;          // clamp keeps loads in-bounds
        const float* p0 = wv + (size_t)gv0 * D_N + dc;
        const float* p1 = wv + (size_t)gv1 * D_N + dc;
        La0 = *(const float4*)(p0);
        Lb0 = *(const float4*)(p0 + 4);
        La1 = *(const float4*)(p1);
        Lb1 = *(const float4*)(p1 + 4);
    };

    auto ISSUE_B = [&](int cn) {
        const _Float16* slab = cB + (size_t)(kb * 10 + cn) * 22528 + tid * 8;
        _Float16* dst = smem + tid * 8;
        #pragma unroll
        for (int it = 0; it < 5; ++it)
            __builtin_amdgcn_global_load_lds(
                (gvoid*)(slab + it * 4096), (lvoid*)(dst + it * 4096), 16, 0, 0);
        if (tid < 256)   // wave-uniform tail (waves 0-3)
            __builtin_amdgcn_global_load_lds(
                (gvoid*)(slab + 5 * 4096), (lvoid*)(dst + 5 * 4096), 16, 0, 0);
    };

    auto CVT = [&](int c, const float4& La, const float4& Lb,
                   h8& qh, h8& ql, h8& ah, h8& al) {
        float xr[8];
        xr[0] = La.x; xr[1] = La.y; xr[2] = La.z; xr[3] = La.w;
        xr[4] = Lb.x; xr[5] = Lb.y; xr[6] = Lb.z; xr[7] = Lb.w;
        if (c == 9) {                          // d tail: chunk 9 covers d 288..319
            if (quad == 1) {                   // need 296..299, zero 300..303
                xr[0] = Lb.x; xr[1] = Lb.y; xr[2] = Lb.z; xr[3] = Lb.w;
                xr[4] = 0.f;  xr[5] = 0.f;  xr[6] = 0.f;  xr[7] = 0.f;
            } else if (quad > 1) {             // d >= 304: all zero
                #pragma unroll
                for (int j = 0; j < 8; ++j) xr[j] = 0.f;
            }
        }
        #pragma unroll
        for (int j = 0; j < 8; ++j) {
            float x = xr[j];
            _Float16 xh = (_Float16)x;
            ah[j] = xh;
            al[j] = (_Float16)(x - (float)xh);
            float xs = x * x;
            _Float16 sh = (_Float16)xs;
            qh[j] = sh;
            ql[j] = (_Float16)(xs - (float)sh);
        }
    };

    // prologue: A(0) in flight
    ISSUE_A(0);

    for (int c = 0; c < 10; ++c) {
        __syncthreads();   // all waves done reading the slab (prev chunk)
        ISSUE_B(c);
        __syncthreads();   // vmcnt(0) drain: slab(c) ready (A regs too)

        // convert current A regs -> fragments (frees the prefetch regs)
        CVT(c, La0, Lb0, qh0, ql0, ah0, al0);
        CVT(c, La1, Lb1, qh1, ql1, ah1, al1);
        // prefetch next chunk's A (hidden under this chunk's compute)
        if (c < 9) ISSUE_A(c + 1);

        const _Float16* Bsp = smem;
        h8 bf[7];
        #define LDB(arr)                                                       \
            _Pragma("unroll")                                                  \
            for (int nt = 0; nt < 7; ++nt) {                                   \
                int n = nt * 16 + lr;                                          \
                bf[nt] = *(const h8*)(Bsp + (arr) * 3584 + n * 32              \
                                      + (((quad + (n >> 1)) & 3) << 3));       \
            }
        #define MF(ACC, MT, FR)                                                \
            _Pragma("unroll")                                                  \
            for (int nt = 0; nt < 7; ++nt)                                     \
                ACC[MT][nt] = __builtin_amdgcn_mfma_f32_16x16x32_f16(          \
                    FR, bf[nt], ACC[MT][nt], 0, 0, 0);

        LDB(0)                    // hi(-0.5 Dinv)
        MF(C1, 0, qh0) MF(C1, 1, qh1) MF(C1, 0, ql0) MF(C1, 1, ql1)
        LDB(1)                    // lo(-0.5 Dinv)
        MF(C1, 0, qh0) MF(C1, 1, qh1)
        LDB(2)                    // hi(mu Dinv)
        MF(C1, 0, ah0) MF(C1, 1, ah1) MF(C1, 0, al0) MF(C1, 1, al1)
        LDB(3)                    // lo(mu Dinv)
        MF(C1, 0, ah0) MF(C1, 1, ah1)
        LDB(4)                    // hi(u)
        MF(C2, 0, ah0) MF(C2, 1, ah1) MF(C2, 0, al0) MF(C2, 1, al1)
        LDB(5)                    // lo(u)
        MF(C2, 0, ah0) MF(C2, 1, ah1)
        #undef LDB
        #undef MF
    }

    // ---- epilogue: combine, transpose via LDS (2 passes of 128 rows) ----
    __syncthreads();   // last chunk's slab reads done before Ct overwrites
    float* Ct = (float*)smem;  // [112][132] fp32 = 59136 B
    const int whalf = w >> 2;
    const int wmL = (w & 3) * 32;
    #pragma unroll
    for (int half = 0; half < 2; ++half) {
        if (whalf == half) {
            #pragma unroll
            for (int nt = 0; nt < 7; ++nt) {
                int nl = nt * 16 + lr;
                int ng = kb * 112 + nl;
                float alv = alphaA[ng], sk = sA[ng], hk = hA[ng];
                #pragma unroll
                for (int mt = 0; mt < 2; ++mt) {
                    f4v c1 = C1[mt][nt], c2 = C2[mt][nt];
                    f4v res;
                    #pragma unroll
                    for (int r = 0; r < 4; ++r) {
                        float t = SC * c2[r] - sk;
                        res[r] = alv + SC * c1[r] + hk * t * t;
                    }
                    *(f4v*)(Ct + nl * 132 + wmL + mt * 16 + quad * 4) = res;
                }
            }
        }
        __syncthreads();
        #pragma unroll
        for (int i = 0; i < 7; ++i) {
            int id = tid + i * 512;        // 0..3583
            int m4 = (id & 31) * 4;
            int nl = id >> 5;              // 0..111
            int kg = kb * 112 + nl;
            if (kg < K_N) {
                f4v val = *(const f4v*)(Ct + nl * 132 + m4);
                int v = v0 + half * 128 + m4;
                if (v + 3 < V_N) {
                    *(float4*)(P + (size_t)kg * V_N + v) =
                        make_float4(val[0], val[1], val[2], val[3]);
                } else {
                    for (int j = 0; j < 4; ++j)
                        if (v + j < V_N) P[(size_t)kg * V_N + v + j] = val[j];
                }
            }
        }
        __syncthreads();
    }
}

// ---------------- kernel C: partial softmax stats (4 parts per topic) ------
__global__ __launch_bounds__(256) void softmax_stats(
    const float* __restrict__ P, float* __restrict__ pm,
    float* __restrict__ ps)
{
    int k = blockIdx.x >> 2, part = blockIdx.x & 3;
    int tid = threadIdx.x;
    const float4* row = (const float4*)(P + (size_t)k * V_N) + part * 6250;
    float m = -INFINITY, s = 0.f;
    for (int i = tid; i < 6250; i += 256) {
        float4 x = row[i];
        float mx = fmaxf(fmaxf(x.x, x.y), fmaxf(x.z, x.w));
        if (mx > m) { s *= __expf(m - mx); m = mx; }
        s += __expf(x.x - m) + __expf(x.y - m)
           + __expf(x.z - m) + __expf(x.w - m);
    }
    __shared__ float ms[256], ss[256];
    ms[tid] = m; ss[tid] = s;
    __syncthreads();
    for (int off = 128; off > 0; off >>= 1) {
        if (tid < off) {
            float mo = ms[tid], so = ss[tid];
            float m2 = ms[tid + off], s2 = ss[tid + off];
            float mn = fmaxf(mo, m2);
            ms[tid] = mn;
            ss[tid] = so * __expf(mo - mn) + s2 * __expf(m2 - mn);
        }
        __syncthreads();
    }
    if (tid == 0) { pm[blockIdx.x] = ms[0]; ps[blockIdx.x] = ss[0]; }
}

// ---------------- kernel C2: yF (MFMA B-layout fp16) + x copy --------------
// yF[kc7][quad4][b256][j8] = x[b][kc*32+quad*8+j] / Z[k]  (0 for k>=200)
// Z merged inline from pm/ps (exact same sequential order as old stats_merge).
__global__ __launch_bounds__(256) void prep_y(
    const float* __restrict__ x,
    const float* __restrict__ pm, const float* __restrict__ ps,
    _Float16* __restrict__ yF, float* __restrict__ out)
{
    int id = blockIdx.x * 256 + threadIdx.x;
    if (id < 57344) {
        int j = id & 7;
        int b = (id >> 3) & 255;
        int q = (id >> 11) & 3;
        int kc = id >> 13;
        int k = kc * 32 + q * 8 + j;
        float v = 0.f;
        if (k < K_N) {
            float m = -INFINITY, s = 0.f;
            #pragma unroll
            for (int p = 0; p < 4; ++p) {
                float m2 = pm[k * 4 + p], s2 = ps[k * 4 + p];
                float mn = fmaxf(m, m2);
                s = s * __expf(m - mn) + s2 * __expf(m2 - mn);
                m = mn;
            }
            v = x[b * K_N + k] / s;
        }
        yF[id] = (_Float16)v;
    } else {
        int id2 = id - 57344;
        if (id2 < B_N * K_N) {
            int b = id2 / K_N, k = id2 % K_N;
            out[(size_t)b * (K_N + V_N) + k] = x[id2];
        }
    }
}

// ---------------- kernel D: out = y @ softmax-weights via fp16 MFMA --------
// b-tile = 256 (full B) -> P read from HBM exactly once; exp once per elem.
// Block: v-tile 64 (M, 4 waves x 1 mt), b-tile 256 (N, 16 nt). grid (1563).
// m_k merged inline from pm (max of 4 parts == old sequential merge).
__global__ __launch_bounds__(256) void out_gemm(
    const float* __restrict__ P, const _Float16* __restrict__ yF,
    const float* __restrict__ pm, float* __restrict__ out)
{
    __shared__ float Es[32][66];        // P chunk minus m_k; stride 66 (2-way reads)
    __shared__ _Float16 Ys[8192];       // y slab for current kc (16 KB)

    const int tid = threadIdx.x;
    const int v0 = blockIdx.x * 64;
    const int lane = tid & 63;
    const int quad = lane >> 4, lr = lane & 15;
    const int w = tid >> 6;
    const int row = w * 16 + lr;        // this wave's v-row within the tile

    f4v acc[16];
    #pragma unroll
    for (int i = 0; i < 16; ++i) acc[i] = (f4v){0.f, 0.f, 0.f, 0.f};

    const int kr = tid >> 3;       // 0..31 (staging row)
    const int vq = tid & 7;

    for (int kc = 0; kc < 7; ++kc) {
        __syncthreads();           // prior compute's LDS reads drained
        // ---- y slab DMA: 8192 halves, linear (layout already MFMA-B) ----
        {
            const _Float16* src = yF + (size_t)kc * 8192 + tid * 8;
            _Float16* dst = Ys + tid * 8;
            #pragma unroll
            for (int it = 0; it < 4; ++it)
                __builtin_amdgcn_global_load_lds(
                    (gvoid*)(src + it * 2048), (lvoid*)(dst + it * 2048),
                    16, 0, 0);
        }
        // ---- stage P chunk (32 k x 64 v), minus m_k ----
        int k = kc * 32 + kr;
        bool kok = k < K_N;
        float mk = 0.f;
        if (kok)
            mk = fmaxf(fmaxf(pm[k * 4], pm[k * 4 + 1]),
                       fmaxf(pm[k * 4 + 2], pm[k * 4 + 3]));
        #pragma unroll
        for (int i = 0; i < 2; ++i) {
            int vv = (vq + i * 8) * 4;
            float4 pv;
            if (kok && v0 + vv + 3 < V_N) {
                pv = *(const float4*)(P + (size_t)k * V_N + v0 + vv);
                pv = make_float4(pv.x - mk, pv.y - mk, pv.z - mk, pv.w - mk);
            } else {
                pv = make_float4(-1e30f, -1e30f, -1e30f, -1e30f);
            }
            *(float2*)&Es[kr][vv]     = make_float2(pv.x, pv.y);
            *(float2*)&Es[kr][vv + 2] = make_float2(pv.z, pv.w);
        }
        __syncthreads();           // drains DMA (vmcnt) + Es writes

        // ---- B fragments from LDS slab: col b = nt*16+lr, k = quad*8+j ----
        h8 yf[16];
        #pragma unroll
        for (int nt = 0; nt < 16; ++nt)
            yf[nt] = *(const h8*)(Ys + ((size_t)(quad * 256) + nt * 16 + lr) * 8);

        // ---- A fragment: row v = row, k = quad*8+j -> exp + cvt ----
        h8 af;
        #pragma unroll
        for (int j = 0; j < 8; ++j)
            af[j] = (_Float16)__expf(Es[quad * 8 + j][row]);

        #pragma unroll
        for (int nt = 0; nt < 16; ++nt)
            acc[nt] = __builtin_amdgcn_mfma_f32_16x16x32_f16(
                af, yf[nt], acc[nt], 0, 0, 0);
    }

    // store: C row = v (quad*4+reg), col = b (lr)
    int v = v0 + w * 16 + quad * 4;
    #pragma unroll
    for (int nt = 0; nt < 16; ++nt) {
        int b = nt * 16 + lr;
        float* dst = out + (size_t)b * (K_N + V_N) + K_N + v;
        f4v a = acc[nt];
        if (v + 3 < V_N) {
            *(float4*)dst = make_float4(a[0], a[1], a[2], a[3]);
        } else {
            for (int j = 0; j < 4; ++j)
                if (v + j < V_N) dst[j] = a[j];
        }
    }
}

// ---------------- launch ----------------
extern "C" void kernel_launch(void* const* d_in, const int* in_sizes, int n_in,
                              void* d_out, int out_size, void* d_ws, size_t ws_size,
                              hipStream_t stream) {
    const float* x    = (const float*)d_in[0];  // (B, K)
    const float* wv   = (const float*)d_in[1];  // (V, D)
    const float* mu   = (const float*)d_in[2];  // (K, D)
    const float* cw   = (const float*)d_in[3];  // (K, D)
    const float* cd   = (const float*)d_in[4];  // (K, D)
    float* out = (float*)d_out;
    float* ws  = (float*)d_ws;

    float* P      = ws + P_OFF;
    _Float16* cB  = (_Float16*)(ws + CB_OFF);
    float* alpha  = ws + ALPHA_OFF;
    float* sArr   = ws + S_OFF;
    float* hic    = ws + HIC_OFF;
    float* pm     = ws + PM_OFF;
    float* ps     = ws + PS_OFF;
    _Float16* yF  = (_Float16*)(ws + YF_OFF);   // overlaps cB (post-logp)

    fused_prep<<<2016, 256, 0, stream>>>(mu, cw, cd, alpha, sArr, hic, cB);

    dim3 gB(2, (V_N + 255) / 256);  // (2, 391)
    logp_mfma<<<gB, 512, 0, stream>>>(wv, cB, alpha, sArr, hic, P);

    softmax_stats<<<K_N * 4, 256, 0, stream>>>(P, pm, ps);
    prep_y<<<(57344 + B_N * K_N + 255) / 256, 256, 0, stream>>>(x, pm, ps, yF, out);

    out_gemm<<<(V_N + 63) / 64, 256, 0, stream>>>(P, yF, pm, out);
}

// Round 6
// 371.456 us; speedup vs baseline: 3.0285x; 1.0454x over previous
//
#include <hip/hip_runtime.h>
#include <math.h>

#define V_N 100000
#define D_N 300
#define K_N 200
#define B_N 256

#define SC 128.0f
#define SC_INV 0.0078125f

typedef _Float16 h4 __attribute__((ext_vector_type(4)));
typedef _Float16 h8 __attribute__((ext_vector_type(8)));
typedef float f4v __attribute__((ext_vector_type(4)));

typedef __attribute__((address_space(1))) const void gvoid;
typedef __attribute__((address_space(3))) void lvoid;

// ---------------- workspace layout (floats) ----------------
static constexpr size_t P_OFF     = 0;
static constexpr size_t CB_OFF    = (size_t)K_N * V_N;            // 20,000,000
static constexpr size_t ALPHA_OFF = CB_OFF + 225280;
static constexpr size_t S_OFF     = ALPHA_OFF + 256;
static constexpr size_t HIC_OFF   = S_OFF + 256;
static constexpr size_t PM_OFF    = HIC_OFF + 256;
static constexpr size_t PS_OFF    = PM_OFF + 800;
static constexpr size_t YF_OFF    = CB_OFF;   // overlap (halves)

// ---------------- kernel A (fused): per-topic scalars + B LDS image --------
__global__ __launch_bounds__(256) void fused_prep(
    const float* __restrict__ mu, const float* __restrict__ w,
    const float* __restrict__ cd,
    float* __restrict__ alpha, float* __restrict__ sArr,
    float* __restrict__ hic, _Float16* __restrict__ cB)
{
    __shared__ float4 red[256];
    int tid = threadIdx.x;
    if (blockIdx.x < 1760) {
        // coef image: chunk slab (kb,c) = 22528 halves; 6 arrays x [n112][32]
        // swizzled: pos p holds source quad q = (p - (n>>1)) & 3; tail 1024 zero.
        // arr: 0/1 = hi/lo(-0.5*Dinv*SC_INV), 2/3 = hi/lo(mu*Dinv*SC_INV), 4/5 = hi/lo(u*SC_INV)
        int id = blockIdx.x * 256 + tid;
        int chunk = id / 22528;
        int rem   = id % 22528;
        int kb = chunk / 10, c = chunk % 10;
        _Float16 outv = (_Float16)0.f;
        if (rem < 21504) {
            int arr = rem / 3584;
            int r2  = rem % 3584;
            int n = r2 >> 5;
            int h = r2 & 31;
            int p = h >> 3, r = h & 7;
            int q = (p - (n >> 1)) & 3;
            int d = c * 32 + q * 8 + r;
            int topic = kb * 112 + n;
            if (topic < K_N && d < D_N) {
                float Di = 1.0f / cd[topic * D_N + d];
                float val;
                if (arr < 2)      val = -0.5f * Di * SC_INV;
                else if (arr < 4) val = mu[topic * D_N + d] * Di * SC_INV;
                else              val = w[topic * D_N + d] * Di * SC_INV;
                _Float16 hi = (_Float16)val;
                outv = (arr & 1) ? (_Float16)(val - (float)hi) : hi;
            }
        }
        cB[id] = outv;
        return;
    }
    int k = blockIdx.x - 1760;
    if (k >= K_N) {
        if (tid == 0) { alpha[k] = 0.f; sArr[k] = 0.f; hic[k] = 0.f; }
        return;
    }
    float capp = 0.f, logd = 0.f, cpart = 0.f, spart = 0.f;
    for (int d = tid; d < D_N; d += 256) {
        float Dg = cd[k * D_N + d];
        float Di = 1.0f / Dg;
        float wvv = w[k * D_N + d];
        float m  = mu[k * D_N + d];
        float u  = wvv * Di;
        capp  += wvv * u;
        logd  += logf(Dg);
        cpart += m * m * Di;
        spart += m * u;
    }
    red[tid] = make_float4(capp, logd, cpart, spart);
    __syncthreads();
    for (int s = 128; s > 0; s >>= 1) {
        if (tid < s) {
            float4 a = red[tid], b = red[tid + s];
            red[tid] = make_float4(a.x + b.x, a.y + b.y, a.z + b.z, a.w + b.w);
        }
        __syncthreads();
    }
    if (tid == 0) {
        float4 r = red[0];
        float cap = 1.0f + r.x;
        float logdet = r.y + logf(cap);
        const float LOG2PI = 1.8378770664093453f;
        alpha[k] = -0.5f * ((float)D_N * LOG2PI + logdet + r.z);
        sArr[k]  = r.w;
        hic[k]   = 0.5f / cap;
    }
}

// ---------------- kernel B: logp via split-fp16 MFMA (v6) ----------------
// Wave tile 16 rows x 112 topics -> acc = 56 regs (C1[7]+C2[7]); total live
// ~115 regs: fits the 128-reg budget -> 4 waves/SIMD. (R2/R5 used 32x112 =
// 112 acc regs + 108 others = 220 -> hard 2 waves/SIMD cap; R4's forced 128
// budget spilled because acc alone was 112.)
// Block M=128 (8 waves), N=112. grid (2, 782), 512 threads.
// B slab single-buffered LDS (45056 B) via global_load_lds, 2 barriers/chunk;
// the co-resident 2nd block (LDS 59.4KB x2 <= 160KB) covers the DMA drain.
// A: direct per-lane loads (one row/lane), latency hidden by 4-wave TLP.
// Per-accumulator MFMA sequence identical to v5 -> bit-identical results.
__global__ __launch_bounds__(512, 4) void logp_mfma(
    const float* __restrict__ wv, const _Float16* __restrict__ cB,
    const float* __restrict__ alphaA, const float* __restrict__ sA,
    const float* __restrict__ hA, float* __restrict__ P)
{
    __shared__ _Float16 smem[29568];   // 59136 B: B slab (45056) / epilogue Ct

    const int tid = threadIdx.x;
    const int kb = blockIdx.x;
    const int v0 = blockIdx.y * 128;
    const int lane = tid & 63;
    const int quad = lane >> 4, lr = lane & 15;
    const int w = tid >> 6;            // wave 0..7

    const int gv0 = min(v0 + w * 16 + lr, V_N - 1);   // this lane's A row

    f4v C1[7], C2[7];
    #pragma unroll
    for (int j = 0; j < 7; ++j) {
        C1[j] = (f4v){0.f, 0.f, 0.f, 0.f};
        C2[j] = (f4v){0.f, 0.f, 0.f, 0.f};
    }

    auto ISSUE_B = [&](int cn) {
        const _Float16* slab = cB + (size_t)(kb * 10 + cn) * 22528 + tid * 8;
        _Float16* dst = smem + tid * 8;
        #pragma unroll
        for (int it = 0; it < 5; ++it)
            __builtin_amdgcn_global_load_lds(
                (gvoid*)(slab + it * 4096), (lvoid*)(dst + it * 4096), 16, 0, 0);
        if (tid < 256)   // wave-uniform tail (waves 0-3)
            __builtin_amdgcn_global_load_lds(
                (gvoid*)(slab + 5 * 4096), (lvoid*)(dst + 5 * 4096), 16, 0, 0);
    };

    for (int c = 0; c < 10; ++c) {
        __syncthreads();   // all waves done reading the slab (prev chunk)
        ISSUE_B(c);
        __syncthreads();   // vmcnt(0) drain: slab(c) ready

        // ---- A: direct load one row x 8 d, split-fp16 in-register ----
        h8 qh, ql, ah, al;
        {
            int db = c * 32 + (quad << 3);
            int dc = db > 292 ? 292 : db;          // clamp keeps loads in-bounds
            const float* p0 = wv + (size_t)gv0 * D_N + dc;
            float4 La = *(const float4*)(p0);
            float4 Lb = *(const float4*)(p0 + 4);
            float xr[8];
            xr[0] = La.x; xr[1] = La.y; xr[2] = La.z; xr[3] = La.w;
            xr[4] = Lb.x; xr[5] = Lb.y; xr[6] = Lb.z; xr[7] = Lb.w;
            if (c == 9) {                          // d tail: chunk 9 = d 288..319
                if (quad == 1) {                   // need 296..299, zero 300..303
                    xr[0] = Lb.x; xr[1] = Lb.y; xr[2] = Lb.z; xr[3] = Lb.w;
                    xr[4] = 0.f;  xr[5] = 0.f;  xr[6] = 0.f;  xr[7] = 0.f;
                } else if (quad > 1) {             // d >= 304: all zero
                    #pragma unroll
                    for (int j = 0; j < 8; ++j) xr[j] = 0.f;
                }
            }
            #pragma unroll
            for (int j = 0; j < 8; ++j) {
                float x = xr[j];
                _Float16 xh = (_Float16)x;
                ah[j] = xh;
                al[j] = (_Float16)(x - (float)xh);
                float xs = x * x;
                _Float16 sh = (_Float16)xs;
                qh[j] = sh;
                ql[j] = (_Float16)(xs - (float)sh);
            }
        }

        // ---- per-nt: 6 ds_read_b128 + 9 MFMAs (acc order == v5) ----
        #pragma unroll
        for (int nt = 0; nt < 7; ++nt) {
            int n = nt * 16 + lr;
            const _Float16* bp = smem + n * 32 + (((quad + (n >> 1)) & 3) << 3);
            h8 b0 = *(const h8*)(bp + 0 * 3584);
            h8 b1 = *(const h8*)(bp + 1 * 3584);
            h8 b2 = *(const h8*)(bp + 2 * 3584);
            h8 b3 = *(const h8*)(bp + 3 * 3584);
            h8 b4 = *(const h8*)(bp + 4 * 3584);
            h8 b5 = *(const h8*)(bp + 5 * 3584);
            f4v c1 = C1[nt], c2 = C2[nt];
            c1 = __builtin_amdgcn_mfma_f32_16x16x32_f16(qh, b0, c1, 0, 0, 0);
            c1 = __builtin_amdgcn_mfma_f32_16x16x32_f16(ql, b0, c1, 0, 0, 0);
            c1 = __builtin_amdgcn_mfma_f32_16x16x32_f16(qh, b1, c1, 0, 0, 0);
            c1 = __builtin_amdgcn_mfma_f32_16x16x32_f16(ah, b2, c1, 0, 0, 0);
            c1 = __builtin_amdgcn_mfma_f32_16x16x32_f16(al, b2, c1, 0, 0, 0);
            c1 = __builtin_amdgcn_mfma_f32_16x16x32_f16(ah, b3, c1, 0, 0, 0);
            c2 = __builtin_amdgcn_mfma_f32_16x16x32_f16(ah, b4, c2, 0, 0, 0);
            c2 = __builtin_amdgcn_mfma_f32_16x16x32_f16(al, b4, c2, 0, 0, 0);
            c2 = __builtin_amdgcn_mfma_f32_16x16x32_f16(ah, b5, c2, 0, 0, 0);
            C1[nt] = c1; C2[nt] = c2;
        }
    }

    // ---- epilogue: combine, transpose via LDS, coalesced store ----
    __syncthreads();   // last chunk's slab reads done before Ct overwrites
    float* Ct = (float*)smem;  // [112][132] fp32 = 59136 B
    #pragma unroll
    for (int nt = 0; nt < 7; ++nt) {
        int nl = nt * 16 + lr;
        int ng = kb * 112 + nl;
        float alv = alphaA[ng], sk = sA[ng], hk = hA[ng];
        f4v c1 = C1[nt], c2 = C2[nt];
        f4v res;
        #pragma unroll
        for (int r = 0; r < 4; ++r) {
            float t = SC * c2[r] - sk;
            res[r] = alv + SC * c1[r] + hk * t * t;
        }
        *(f4v*)(Ct + nl * 132 + w * 16 + quad * 4) = res;
    }
    __syncthreads();
    #pragma unroll
    for (int i = 0; i < 7; ++i) {
        int id = tid + i * 512;        // 0..3583
        int m4 = (id & 31) * 4;        // 0..124
        int nl = id >> 5;              // 0..111
        int kg = kb * 112 + nl;
        if (kg < K_N) {
            f4v val = *(const f4v*)(Ct + nl * 132 + m4);
            int v = v0 + m4;
            if (v + 3 < V_N) {
                *(float4*)(P + (size_t)kg * V_N + v) =
                    make_float4(val[0], val[1], val[2], val[3]);
            } else {
                for (int j = 0; j < 4; ++j)
                    if (v + j < V_N) P[(size_t)kg * V_N + v + j] = val[j];
            }
        }
    }
}

// ---------------- kernel C: partial softmax stats (4 parts per topic) ------
__global__ __launch_bounds__(256) void softmax_stats(
    const float* __restrict__ P, float* __restrict__ pm,
    float* __restrict__ ps)
{
    int k = blockIdx.x >> 2, part = blockIdx.x & 3;
    int tid = threadIdx.x;
    const float4* row = (const float4*)(P + (size_t)k * V_N) + part * 6250;
    float m = -INFINITY, s = 0.f;
    for (int i = tid; i < 6250; i += 256) {
        float4 x = row[i];
        float mx = fmaxf(fmaxf(x.x, x.y), fmaxf(x.z, x.w));
        if (mx > m) { s *= __expf(m - mx); m = mx; }
        s += __expf(x.x - m) + __expf(x.y - m)
           + __expf(x.z - m) + __expf(x.w - m);
    }
    __shared__ float ms[256], ss[256];
    ms[tid] = m; ss[tid] = s;
    __syncthreads();
    for (int off = 128; off > 0; off >>= 1) {
        if (tid < off) {
            float mo = ms[tid], so = ss[tid];
            float m2 = ms[tid + off], s2 = ss[tid + off];
            float mn = fmaxf(mo, m2);
            ms[tid] = mn;
            ss[tid] = so * __expf(mo - mn) + s2 * __expf(m2 - mn);
        }
        __syncthreads();
    }
    if (tid == 0) { pm[blockIdx.x] = ms[0]; ps[blockIdx.x] = ss[0]; }
}

// ---------------- kernel C2: yF (MFMA B-layout fp16) + x copy --------------
__global__ __launch_bounds__(256) void prep_y(
    const float* __restrict__ x,
    const float* __restrict__ pm, const float* __restrict__ ps,
    _Float16* __restrict__ yF, float* __restrict__ out)
{
    int id = blockIdx.x * 256 + threadIdx.x;
    if (id < 57344) {
        int j = id & 7;
        int b = (id >> 3) & 255;
        int q = (id >> 11) & 3;
        int kc = id >> 13;
        int k = kc * 32 + q * 8 + j;
        float v = 0.f;
        if (k < K_N) {
            float m = -INFINITY, s = 0.f;
            #pragma unroll
            for (int p = 0; p < 4; ++p) {
                float m2 = pm[k * 4 + p], s2 = ps[k * 4 + p];
                float mn = fmaxf(m, m2);
                s = s * __expf(m - mn) + s2 * __expf(m2 - mn);
                m = mn;
            }
            v = x[b * K_N + k] / s;
        }
        yF[id] = (_Float16)v;
    } else {
        int id2 = id - 57344;
        if (id2 < B_N * K_N) {
            int b = id2 / K_N, k = id2 % K_N;
            out[(size_t)b * (K_N + V_N) + k] = x[id2];
        }
    }
}

// ---------------- kernel D: out = y @ softmax-weights via fp16 MFMA --------
__global__ __launch_bounds__(256) void out_gemm(
    const float* __restrict__ P, const _Float16* __restrict__ yF,
    const float* __restrict__ pm, float* __restrict__ out)
{
    __shared__ float Es[32][66];        // P chunk minus m_k; stride 66
    __shared__ _Float16 Ys[8192];       // y slab for current kc (16 KB)

    const int tid = threadIdx.x;
    const int v0 = blockIdx.x * 64;
    const int lane = tid & 63;
    const int quad = lane >> 4, lr = lane & 15;
    const int w = tid >> 6;
    const int row = w * 16 + lr;

    f4v acc[16];
    #pragma unroll
    for (int i = 0; i < 16; ++i) acc[i] = (f4v){0.f, 0.f, 0.f, 0.f};

    const int kr = tid >> 3;
    const int vq = tid & 7;

    for (int kc = 0; kc < 7; ++kc) {
        __syncthreads();
        {
            const _Float16* src = yF + (size_t)kc * 8192 + tid * 8;
            _Float16* dst = Ys + tid * 8;
            #pragma unroll
            for (int it = 0; it < 4; ++it)
                __builtin_amdgcn_global_load_lds(
                    (gvoid*)(src + it * 2048), (lvoid*)(dst + it * 2048),
                    16, 0, 0);
        }
        int k = kc * 32 + kr;
        bool kok = k < K_N;
        float mk = 0.f;
        if (kok)
            mk = fmaxf(fmaxf(pm[k * 4], pm[k * 4 + 1]),
                       fmaxf(pm[k * 4 + 2], pm[k * 4 + 3]));
        #pragma unroll
        for (int i = 0; i < 2; ++i) {
            int vv = (vq + i * 8) * 4;
            float4 pv;
            if (kok && v0 + vv + 3 < V_N) {
                pv = *(const float4*)(P + (size_t)k * V_N + v0 + vv);
                pv = make_float4(pv.x - mk, pv.y - mk, pv.z - mk, pv.w - mk);
            } else {
                pv = make_float4(-1e30f, -1e30f, -1e30f, -1e30f);
            }
            *(float2*)&Es[kr][vv]     = make_float2(pv.x, pv.y);
            *(float2*)&Es[kr][vv + 2] = make_float2(pv.z, pv.w);
        }
        __syncthreads();

        h8 yf[16];
        #pragma unroll
        for (int nt = 0; nt < 16; ++nt)
            yf[nt] = *(const h8*)(Ys + ((size_t)(quad * 256) + nt * 16 + lr) * 8);

        h8 af;
        #pragma unroll
        for (int j = 0; j < 8; ++j)
            af[j] = (_Float16)__expf(Es[quad * 8 + j][row]);

        #pragma unroll
        for (int nt = 0; nt < 16; ++nt)
            acc[nt] = __builtin_amdgcn_mfma_f32_16x16x32_f16(
                af, yf[nt], acc[nt], 0, 0, 0);
    }

    int v = v0 + w * 16 + quad * 4;
    #pragma unroll
    for (int nt = 0; nt < 16; ++nt) {
        int b = nt * 16 + lr;
        float* dst = out + (size_t)b * (K_N + V_N) + K_N + v;
        f4v a = acc[nt];
        if (v + 3 < V_N) {
            *(float4*)dst = make_float4(a[0], a[1], a[2], a[3]);
        } else {
            for (int j = 0; j < 4; ++j)
                if (v + j < V_N) dst[j] = a[j];
        }
    }
}

// ---------------- launch ----------------
extern "C" void kernel_launch(void* const* d_in, const int* in_sizes, int n_in,
                              void* d_out, int out_size, void* d_ws, size_t ws_size,
                              hipStream_t stream) {
    const float* x    = (const float*)d_in[0];  // (B, K)
    const float* wv   = (const float*)d_in[1];  // (V, D)
    const float* mu   = (const float*)d_in[2];  // (K, D)
    const float* cw   = (const float*)d_in[3];  // (K, D)
    const float* cd   = (const float*)d_in[4];  // (K, D)
    float* out = (float*)d_out;
    float* ws  = (float*)d_ws;

    float* P      = ws + P_OFF;
    _Float16* cB  = (_Float16*)(ws + CB_OFF);
    float* alpha  = ws + ALPHA_OFF;
    float* sArr   = ws + S_OFF;
    float* hic    = ws + HIC_OFF;
    float* pm     = ws + PM_OFF;
    float* ps     = ws + PS_OFF;
    _Float16* yF  = (_Float16*)(ws + YF_OFF);   // overlaps cB (post-logp)

    fused_prep<<<2016, 256, 0, stream>>>(mu, cw, cd, alpha, sArr, hic, cB);

    dim3 gB(2, (V_N + 127) / 128);  // (2, 782)
    logp_mfma<<<gB, 512, 0, stream>>>(wv, cB, alpha, sArr, hic, P);

    softmax_stats<<<K_N * 4, 256, 0, stream>>>(P, pm, ps);
    prep_y<<<(57344 + B_N * K_N + 255) / 256, 256, 0, stream>>>(x, pm, ps, yF, out);

    out_gemm<<<(V_N + 63) / 64, 256, 0, stream>>>(P, yF, pm, out);
}